// Round 2
// baseline (659.479 us; speedup 1.0000x reference)
//
#include <hip/hip_runtime.h>
#include <hip/hip_bf16.h>
#include <cstdint>
#include <cstddef>

#define K5 5
#define BNEPS 1e-5f

typedef __attribute__((ext_vector_type(8))) short short8v;
typedef __attribute__((ext_vector_type(4))) float float4v;

// 16B vector load with only 4B alignment guarantee
struct __attribute__((packed, aligned(4))) f4u { float4v v; };

// ---- weight prep: fp32 [co][ci][tap] -> bf16 [co][kk], kk=tap*CIN+ci,
//      rows padded to MROWS (>=COUT) with zeros, k padded to KPAD with zeros.
template<int CIN, int COUT, int MROWS, int KPAD>
__device__ inline void wprep_body(const float* __restrict__ w,
                                  short* __restrict__ wb, int blk, int tid) {
    int idx = blk * 256 + tid;
    if (idx >= MROWS * KPAD) return;
    int co = idx / KPAD, kk = idx - co * KPAD;
    int tap = kk / CIN, ci = kk & (CIN - 1);
    float v = (co < COUT && tap < K5) ? w[((size_t)co * CIN + ci) * K5 + tap] : 0.f;
    __hip_bfloat16 h = __float2bfloat16(v);
    wb[idx] = *(short*)&h;
}

__global__ __launch_bounds__(256) void wprep_all_ker(
    const float* __restrict__ w0, const float* __restrict__ w1,
    const float* __restrict__ w2, const float* __restrict__ w3,
    const float* __restrict__ w4,
    short* __restrict__ wb0, short* __restrict__ wb1, short* __restrict__ wb2,
    short* __restrict__ wb3, short* __restrict__ wb4) {
    int b = blockIdx.x, t = threadIdx.x;
    if (b < 160)      wprep_body<128, 64, 64, 640>(w0, wb0, b, t);
    else if (b < 200) wprep_body<64, 32, 32, 320>(w1, wb1, b - 160, t);
    else if (b < 210) wprep_body<32, 16, 16, 160>(w2, wb2, b - 200, t);
    else if (b < 216) wprep_body<16, 8, 16, 96>(w3, wb3, b - 210, t);
    else              wprep_body<8, 3, 16, 64>(w4, wb4, b - 216, t);
}

// ---- MFMA conv: (opt up2 of input) -> reflect-pad dilated conv -> BN+ReLU|bias
// GEMM D[co][t] = W[co][kk] * X[kk][t], kk = tap*CIN+ci.
// Staging vectorized: one (possibly unaligned) dwordx4 global read feeds a
// 4-t span; UP path exploits u0 even -> x[m-1..m+2] covers all 4 interp
// outputs. Scalar fallback (original code) for reflect/clamp edge spans.
template<int CIN, int COUT, int DIL, int LOUT, bool UP_IN, int T_TILE, int WT,
         bool HAS_BN, int MW>
__global__ __launch_bounds__(256, MW) void conv_mfma2_ker(
    const float* __restrict__ in, const short* __restrict__ wb,
    const float* __restrict__ gg, const float* __restrict__ bb,
    const float* __restrict__ mm, const float* __restrict__ vv,
    float* __restrict__ out)
{
    constexpr int P = 2 * DIL;                  // ((K-1)*d+1)//2 == 2d
    constexpr int XT = T_TILE + 4 * DIL;
    constexpr int ROWW = CIN + 8;               // shorts; multiple of 8 -> 16B rows
    constexpr int K = CIN * K5;
    constexpr int KPAD = ((K + 31) / 32) * 32;
    constexpr int NSTEP = KPAD / 32;
    constexpr int MT = (COUT + 15) / 16;        // co tiles (zero-padded rows)
    constexpr int WCOT = MT;                    // co-tiles per wave (WCO=1)
    constexpr int TN = T_TILE / (16 * WT);      // t-tiles per wave
    constexpr int LIN = LOUT;
    constexpr int LIN_BASE = UP_IN ? (LOUT / 2) : LOUT;
    static_assert(XT % 4 == 0, "XT must be multiple of 4");
    static_assert(T_TILE % (16 * WT) == 0, "tile split");
    constexpr int T4 = XT / 4;
    constexpr int NITEM = T4 * (CIN / 8);

    __shared__ short sx[XT * ROWW];
    __shared__ float ssc[COUT], ssh[COUT];

    const int n = blockIdx.x;
    const int t0 = blockIdx.y * T_TILE;
    const int tid = threadIdx.x;

    if (tid < COUT) {
        if constexpr (HAS_BN) {
            float inv = gg[tid] * rsqrtf(vv[tid] + BNEPS);
            ssc[tid] = inv;
            ssh[tid] = bb[tid] - mm[tid] * inv;
        } else {
            ssc[tid] = 1.f;
            ssh[tid] = bb[tid];
        }
    }

    // ---- stage sx[t][ci]: vectorized 4-t spans per item ----
    for (int uidx = tid; uidx < NITEM; uidx += 256) {
        int t4 = uidx % T4;
        int ci0 = (uidx / T4) * 8;
        const int u0 = t0 - P + 4 * t4;         // always even (P,t0,4*t4 even)
        const float* base = in + ((size_t)n * CIN + ci0) * LIN_BASE;
        short8v rows[4];
        bool fast;
        if constexpr (UP_IN) fast = (u0 >= 2) && (u0 <= LIN - 6);
        else                 fast = (u0 >= 0) && (u0 + 3 <= LIN - 1);
        if (fast) {
            if constexpr (UP_IN) {
                const int m = u0 >> 1;
#pragma unroll
                for (int j = 0; j < 8; ++j) {
                    f4u xv = *(const f4u*)(base + (size_t)j * LIN_BASE + (m - 1));
                    float o0 = 0.25f * xv.v[0] + 0.75f * xv.v[1];
                    float o1 = 0.75f * xv.v[1] + 0.25f * xv.v[2];
                    float o2 = 0.25f * xv.v[1] + 0.75f * xv.v[2];
                    float o3 = 0.75f * xv.v[2] + 0.25f * xv.v[3];
                    __hip_bfloat16 ha = __float2bfloat16(o0);
                    __hip_bfloat16 hb = __float2bfloat16(o1);
                    __hip_bfloat16 hc = __float2bfloat16(o2);
                    __hip_bfloat16 hd = __float2bfloat16(o3);
                    rows[0][j] = *(short*)&ha; rows[1][j] = *(short*)&hb;
                    rows[2][j] = *(short*)&hc; rows[3][j] = *(short*)&hd;
                }
            } else {
#pragma unroll
                for (int j = 0; j < 8; ++j) {
                    f4u xv = *(const f4u*)(base + (size_t)j * LIN_BASE + u0);
#pragma unroll
                    for (int r = 0; r < 4; ++r) {
                        __hip_bfloat16 hh = __float2bfloat16(xv.v[r]);
                        rows[r][j] = *(short*)&hh;
                    }
                }
            }
        } else {
#pragma unroll
            for (int r = 0; r < 4; ++r) {
                int u = u0 + r;
                u = (u < 0) ? -u : u;
                u = (u >= LIN) ? (2 * (LIN - 1) - u) : u;
                if constexpr (UP_IN) {
                    int i = u >> 1;
                    int ia, ib; float wa, wbw;
                    if (u & 1) { ia = i; ib = (i + 1 < LIN_BASE) ? i + 1 : LIN_BASE - 1; wa = 0.75f; wbw = 0.25f; }
                    else if (i == 0) { ia = 0; ib = 0; wa = 1.0f; wbw = 0.0f; }
                    else { ia = i - 1; ib = i; wa = 0.25f; wbw = 0.75f; }
#pragma unroll
                    for (int j = 0; j < 8; ++j) {
                        float v = wa * base[(size_t)j * LIN_BASE + ia] + wbw * base[(size_t)j * LIN_BASE + ib];
                        __hip_bfloat16 hh = __float2bfloat16(v);
                        rows[r][j] = *(short*)&hh;
                    }
                } else {
#pragma unroll
                    for (int j = 0; j < 8; ++j) {
                        __hip_bfloat16 hh = __float2bfloat16(base[(size_t)j * LIN_BASE + u]);
                        rows[r][j] = *(short*)&hh;
                    }
                }
            }
        }
        short* dst = sx + (4 * t4) * ROWW + ci0;
        *(short8v*)(dst) = rows[0];
        *(short8v*)(dst + ROWW) = rows[1];
        *(short8v*)(dst + 2 * ROWW) = rows[2];
        *(short8v*)(dst + 3 * ROWW) = rows[3];
    }
    __syncthreads();

    const int wvi = tid >> 6;
    const int lane = tid & 63;
    const int ln = lane & 15;     // A: m=co row; B: n=t; D: col=t
    const int q = lane >> 4;      // k sub-block (q*8..q*8+7)
    const int tw = wvi * (TN * 16);

    float4v acc[WCOT][TN];
#pragma unroll
    for (int c = 0; c < WCOT; ++c)
#pragma unroll
        for (int j = 0; j < TN; ++j)
            acc[c][j] = (float4v){0.f, 0.f, 0.f, 0.f};

    const short* arow[WCOT];
#pragma unroll
    for (int c = 0; c < WCOT; ++c)
        arow[c] = wb + ((size_t)(c * 16 + ln)) * KPAD + q * 8;

    short8v acur[WCOT], anx[WCOT];
#pragma unroll
    for (int c = 0; c < WCOT; ++c)
        acur[c] = *(const short8v*)(arow[c]);

#pragma unroll 1
    for (int s = 0; s < NSTEP; ++s) {
        if (s + 1 < NSTEP) {
#pragma unroll
            for (int c = 0; c < WCOT; ++c)
                anx[c] = *(const short8v*)(arow[c] + (s + 1) * 32);
        }
        const int kk = s * 32 + q * 8;
        int tap = kk / CIN;                    // pow2 -> shift
        const int ci0 = kk & (CIN - 1);
        if constexpr (KPAD != K) {
            tap = (tap < K5) ? tap : (K5 - 1); // clamp addr for padded region
        }
        short8v b[TN];
#pragma unroll
        for (int j = 0; j < TN; ++j)
            b[j] = *(const short8v*)(sx + (tw + j * 16 + ln + tap * DIL) * ROWW + ci0);
        if constexpr (KPAD != K) {
            if (kk >= K) {
                short8v z = {0, 0, 0, 0, 0, 0, 0, 0};
#pragma unroll
                for (int j = 0; j < TN; ++j) b[j] = z;
            }
        }
#pragma unroll
        for (int c = 0; c < WCOT; ++c)
#pragma unroll
            for (int j = 0; j < TN; ++j)
                acc[c][j] = __builtin_amdgcn_mfma_f32_16x16x32_bf16(acur[c], b[j], acc[c][j], 0, 0, 0);
#pragma unroll
        for (int c = 0; c < WCOT; ++c)
            acur[c] = anx[c];
    }

    // epilogue: D col(ln)=t (coalesced), row(q*4+r)=co
    float* ob = out + (size_t)n * COUT * LOUT + t0 + tw + ln;
#pragma unroll
    for (int c = 0; c < WCOT; ++c)
#pragma unroll
        for (int j = 0; j < TN; ++j) {
            float4v v = acc[c][j];
#pragma unroll
            for (int r = 0; r < 4; ++r) {
                int co = c * 16 + q * 4 + r;
                if ((COUT % 16 == 0) || co < COUT) {
                    float val = v[r] * ssc[co] + ssh[co];
                    if constexpr (HAS_BN) val = fmaxf(val, 0.f);
                    ob[(size_t)co * LOUT + j * 16] = val;
                }
            }
        }
}

// ---- final upsample + transpose + loss --------------------------------------
__global__ __launch_bounds__(256) void up_loss_ker(
    const float* __restrict__ h4, const float* __restrict__ targets,
    float* __restrict__ out, float* __restrict__ loss_sum, int* __restrict__ flags)
{
    constexpr int L = 16384, LO = 32768;
    const int bt = blockIdx.x;
    const int t0 = blockIdx.y * 256;
    const int tid = threadIdx.x;
    const int i0 = t0 >> 1;

    __shared__ float sh[3 * 8 * 132];
    __shared__ int snz[8];
    __shared__ float swv[4];

    // stage 24 rows x 132 floats (i0-1 .. i0+130), float4-vectorized
    {
        const bool interior = (i0 >= 1) && (i0 + 130 <= L - 1);
        for (int idx = tid; idx < 24 * 33; idx += 256) {
            int row = idx / 33;
            int qd = idx - row * 33;
            int c = row >> 3, s = row & 7;
            int nn = bt * 8 + s;
            const float* src = h4 + ((size_t)nn * 3 + c) * L;
            int bi0 = i0 - 1 + 4 * qd;
            float4v v;
            if (interior) {
                v = ((const f4u*)(src + bi0))->v;
            } else {
#pragma unroll
                for (int k = 0; k < 4; ++k) {
                    int bi = bi0 + k;
                    bi = bi < 0 ? 0 : (bi > L - 1 ? L - 1 : bi);
                    v[k] = src[bi];
                }
            }
            *(float4v*)(sh + row * 132 + 4 * qd) = v;
        }
    }
    if (tid < 8) snz[tid] = 0;
    __syncthreads();

    const int tl = tid >> 1;            // 0..127 -> t offset
    const int st4 = (tid & 1) * 4;      // st half

    float lsum = 0.f;
    int nzm = 0;
#pragma unroll
    for (int rr = 0; rr < 2; ++rr) {
        int t = t0 + rr * 128 + tl;
        int li = (t >> 1) - i0 + 1;
        float o[3][4];
#pragma unroll
        for (int c = 0; c < 3; ++c)
#pragma unroll
            for (int s = 0; s < 4; ++s) {
                const float* row = sh + ((c << 3) + st4 + s) * 132;
                float v;
                if (t & 1) v = 0.75f * row[li] + 0.25f * row[li + 1];
                else       v = 0.25f * row[li - 1] + 0.75f * row[li];
                o[c][s] = v;
            }
        float tg[3][4];
#pragma unroll
        for (int c = 0; c < 3; ++c) {
            size_t obase = (((size_t)bt * 3 + c) * LO + t) * 8 + st4;
            float4v ov = { o[c][0], o[c][1], o[c][2], o[c][3] };
            *(float4v*)(out + obase) = ov;
            float4v tv = *(const float4v*)(targets + obase);
            tg[c][0] = tv[0]; tg[c][1] = tv[1]; tg[c][2] = tv[2]; tg[c][3] = tv[3];
        }
#pragma unroll
        for (int s = 0; s < 4; ++s) {
            float a0 = o[0][s], a1 = o[1][s], a2 = o[2][s];
            float mx = fmaxf(a0, fmaxf(a1, a2));
            float e0 = __expf(a0 - mx), e1 = __expf(a1 - mx), e2 = __expf(a2 - mx);
            float lse = mx + __logf(e0 + e1 + e2);
            lsum += tg[0][s] * (lse - a0) + tg[1][s] * (lse - a1) + tg[2][s] * (lse - a2);
            if ((tg[0][s] != 0.f) | (tg[1][s] != 0.f) | (tg[2][s] != 0.f)) nzm |= 1 << s;
        }
    }
    if (nzm) {
#pragma unroll
        for (int s = 0; s < 4; ++s) if (nzm & (1 << s)) snz[st4 + s] = 1;
    }

#pragma unroll
    for (int off = 32; off > 0; off >>= 1) lsum += __shfl_down(lsum, off, 64);
    if ((tid & 63) == 0) swv[tid >> 6] = lsum;
    __syncthreads();
    if (tid == 0) atomicAdd(loss_sum, swv[0] + swv[1] + swv[2] + swv[3]);
    if (tid < 8 && snz[tid]) atomicOr(&flags[bt * 8 + tid], 1);
}

__global__ __launch_bounds__(256) void finalize_ker(
    const int* __restrict__ flags, const float* __restrict__ loss_sum,
    float* __restrict__ out_loss)
{
    __shared__ int s[256];
    s[threadIdx.x] = flags[threadIdx.x] ? 1 : 0;
    __syncthreads();
    for (int off = 128; off > 0; off >>= 1) {
        if (threadIdx.x < off) s[threadIdx.x] += s[threadIdx.x + off];
        __syncthreads();
    }
    if (threadIdx.x == 0) out_loss[0] = loss_sum[0] / ((float)s[0] * 32768.0f);
}

extern "C" void kernel_launch(void* const* d_in, const int* in_sizes, int n_in,
                              void* d_out, int out_size, void* d_ws, size_t ws_size,
                              hipStream_t stream)
{
    const float* x  = (const float*)d_in[0];
    const float* tg = (const float*)d_in[1];
    const float* w0 = (const float*)d_in[2];
    const float* g0 = (const float*)d_in[3];
    const float* b0 = (const float*)d_in[4];
    const float* m0 = (const float*)d_in[5];
    const float* v0 = (const float*)d_in[6];
    const float* w1 = (const float*)d_in[7];
    const float* g1 = (const float*)d_in[8];
    const float* b1 = (const float*)d_in[9];
    const float* m1 = (const float*)d_in[10];
    const float* v1 = (const float*)d_in[11];
    const float* w2 = (const float*)d_in[12];
    const float* g2 = (const float*)d_in[13];
    const float* b2 = (const float*)d_in[14];
    const float* m2 = (const float*)d_in[15];
    const float* v2 = (const float*)d_in[16];
    const float* w3 = (const float*)d_in[17];
    const float* g3 = (const float*)d_in[18];
    const float* b3 = (const float*)d_in[19];
    const float* m3 = (const float*)d_in[20];
    const float* v3 = (const float*)d_in[21];
    const float* w_out = (const float*)d_in[22];
    const float* b_out = (const float*)d_in[23];
    float* outp = (float*)d_out;

    char* ws = (char*)d_ws;
    int* flags = (int*)ws;                           // [0,1024)
    float* loss_sum = (float*)(ws + 1024);
    short* wb0 = (short*)(ws + 4096);                // 64 x 640  = 81920 B
    short* wb1 = (short*)(ws + 86016);               // 32 x 320  = 20480 B
    short* wb2 = (short*)(ws + 106496);               // 16 x 160  =  5120 B
    short* wb3 = (short*)(ws + 111616);              // 16 x 96   =  3072 B
    short* wb4 = (short*)(ws + 114688);              // 16 x 64   =  2048 B
    const size_t BUF_OFF = 131072;
    const size_t BUFN = (size_t)16777216;            // floats per ping-pong buffer
    float* bufA = (float*)(ws + BUF_OFF);
    float* bufB = (ws_size >= BUF_OFF + 2 * BUFN * 4)
                      ? (bufA + BUFN)
                      : (float*)d_out;               // d_out as scratch fallback

    hipMemsetAsync(d_ws, 0, 4096, stream);

    wprep_all_ker<<<220, 256, 0, stream>>>(w0, w1, w2, w3, w_out,
                                           wb0, wb1, wb2, wb3, wb4);

    // h0 (256,64,1024)   T_TILE=64, ~19KB LDS, WCOT=4, TN=1, target 8 blk/CU
    conv_mfma2_ker<128, 64, 1, 1024, false, 64, 4, true, 6>
        <<<dim3(256, 16), 256, 0, stream>>>(x, wb0, g0, b0, m0, v0, bufA);
    // h1 (256,32,2048)   T_TILE=128, ~20KB LDS, WCOT=2, TN=2
    conv_mfma2_ker<64, 32, 2, 2048, true, 128, 4, true, 6>
        <<<dim3(256, 16), 256, 0, stream>>>(bufA, wb1, g1, b1, m1, v1, bufB);
    // h2 (256,16,4096)   T_TILE=256, ~22KB LDS, WCOT=1, TN=4
    conv_mfma2_ker<32, 16, 4, 4096, true, 256, 4, true, 8>
        <<<dim3(256, 16), 256, 0, stream>>>(bufB, wb2, g2, b2, m2, v2, bufA);
    // h3 (256,8,8192)    T_TILE=256, ~14KB LDS, WCOT=1, TN=4
    conv_mfma2_ker<16, 8, 8, 8192, true, 256, 4, true, 8>
        <<<dim3(256, 32), 256, 0, stream>>>(bufA, wb3, g3, b3, m3, v3, bufB);
    // h4 (256,3,16384)   T_TILE=256, ~10KB LDS, WCOT=1, TN=4
    conv_mfma2_ker<8, 3, 16, 16384, true, 256, 4, false, 8>
        <<<dim3(256, 64), 256, 0, stream>>>(bufB, wb4, b_out, b_out, b_out, b_out, bufA);
    // out + loss
    up_loss_ker<<<dim3(32, 128), 256, 0, stream>>>(bufA, tg, outp, loss_sum, flags);
    finalize_ker<<<1, 256, 0, stream>>>(flags, loss_sum, outp + (size_t)(out_size - 1));
}

// Round 3
// 561.721 us; speedup vs baseline: 1.1740x; 1.1740x over previous
//
#include <hip/hip_runtime.h>
#include <hip/hip_bf16.h>
#include <cstdint>
#include <cstddef>

#define K5 5
#define BNEPS 1e-5f

typedef __attribute__((ext_vector_type(8))) short short8v;
typedef __attribute__((ext_vector_type(4))) short short4v;
typedef __attribute__((ext_vector_type(4))) float float4v;

// 16B vector load with only 4B alignment guarantee
struct __attribute__((packed, aligned(4))) f4u { float4v v; };

__device__ inline float bf2f(short s) {
    __hip_bfloat16 h = *(__hip_bfloat16*)&s;
    return __bfloat162float(h);
}
__device__ inline short f2bf(float f) {
    __hip_bfloat16 h = __float2bfloat16(f);
    return *(short*)&h;
}

// ---- weight prep: fp32 [co][ci][tap] -> bf16 [co][kk], kk=tap*CIN+ci,
//      rows padded to MROWS (>=COUT) with zeros, k padded to KPAD with zeros.
template<int CIN, int COUT, int MROWS, int KPAD>
__device__ inline void wprep_body(const float* __restrict__ w,
                                  short* __restrict__ wb, int blk, int tid) {
    int idx = blk * 256 + tid;
    if (idx >= MROWS * KPAD) return;
    int co = idx / KPAD, kk = idx - co * KPAD;
    int tap = kk / CIN, ci = kk & (CIN - 1);
    float v = (co < COUT && tap < K5) ? w[((size_t)co * CIN + ci) * K5 + tap] : 0.f;
    wb[idx] = f2bf(v);
}

__global__ __launch_bounds__(256) void wprep_all_ker(
    const float* __restrict__ w0, const float* __restrict__ w1,
    const float* __restrict__ w2, const float* __restrict__ w3,
    const float* __restrict__ w4,
    short* __restrict__ wb0, short* __restrict__ wb1, short* __restrict__ wb2,
    short* __restrict__ wb3, short* __restrict__ wb4) {
    int b = blockIdx.x, t = threadIdx.x;
    if (b < 160)      wprep_body<128, 64, 64, 640>(w0, wb0, b, t);
    else if (b < 200) wprep_body<64, 32, 32, 320>(w1, wb1, b - 160, t);
    else if (b < 210) wprep_body<32, 16, 16, 160>(w2, wb2, b - 200, t);
    else if (b < 216) wprep_body<16, 8, 16, 96>(w3, wb3, b - 210, t);
    else              wprep_body<8, 3, 16, 64>(w4, wb4, b - 216, t);
}

// ---- MFMA conv, bf16 [n][t][c] activation layout ----------------------------
// GEMM D[co][t] = W[co][kk] * X[kk][t], kk = tap*CIN+ci.
// IN_MODE  0: fp32 [n][c][t] input, no upsample (h0, external x)
//          1: bf16 [n][t][c] input, x2 linear upsample at staging (h1..h4)
// OUT_MODE 0: bf16 [n][t][c] output (h0..h3)
//          1: fp32 [n][c][t] output (h4 -> up_loss, unchanged interface)
template<int CIN, int COUT, int DIL, int LOUT, int T_TILE, int WT,
         bool HAS_BN, int IN_MODE, int OUT_MODE>
__global__ __launch_bounds__(256) void conv_ker(
    const void* __restrict__ in_, const short* __restrict__ wb,
    const float* __restrict__ gg, const float* __restrict__ bb,
    const float* __restrict__ mm, const float* __restrict__ vv,
    void* __restrict__ out_)
{
    constexpr int P = 2 * DIL;                  // ((K-1)*d+1)//2 == 2d
    constexpr int XT = T_TILE + 4 * DIL;
    constexpr int ROWW = CIN + 8;               // shorts; multiple of 8 -> 16B rows
    constexpr int K = CIN * K5;
    constexpr int KPAD = ((K + 31) / 32) * 32;
    constexpr int NSTEP = KPAD / 32;
    constexpr int WCOT = (COUT + 15) / 16;      // co tiles (zero-padded rows)
    constexpr int TN = T_TILE / (16 * WT);      // t-tiles per wave
    constexpr int LIN = LOUT;
    constexpr int LIN_BASE = (IN_MODE == 1) ? (LOUT / 2) : LOUT;
    static_assert(T_TILE % (16 * WT) == 0, "tile split");

    __shared__ short sx[XT * ROWW];
    __shared__ float ssc[COUT], ssh[COUT];

    const int n = blockIdx.x;
    const int t0 = blockIdx.y * T_TILE;
    const int tid = threadIdx.x;

    if (tid < COUT) {
        if constexpr (HAS_BN) {
            float inv = gg[tid] * rsqrtf(vv[tid] + BNEPS);
            ssc[tid] = inv;
            ssh[tid] = bb[tid] - mm[tid] * inv;
        } else {
            ssc[tid] = 1.f;
            ssh[tid] = bb[tid];
        }
    }

    if constexpr (IN_MODE == 0) {
        // fp32 [n][c][t] staging, 4-t vectorized spans (no upsample)
        static_assert(XT % 4 == 0, "XT mult of 4");
        constexpr int T4 = XT / 4;
        constexpr int NITEM = T4 * (CIN / 8);
        const float* in = (const float*)in_;
        for (int uidx = tid; uidx < NITEM; uidx += 256) {
            int t4 = uidx % T4;
            int ci0 = (uidx / T4) * 8;
            const int u0 = t0 - P + 4 * t4;
            const float* base = in + ((size_t)n * CIN + ci0) * LIN_BASE;
            short8v rows[4];
            bool fast = (u0 >= 0) && (u0 + 3 <= LIN - 1);
            if (fast) {
#pragma unroll
                for (int j = 0; j < 8; ++j) {
                    f4u xv = *(const f4u*)(base + (size_t)j * LIN_BASE + u0);
#pragma unroll
                    for (int r = 0; r < 4; ++r) rows[r][j] = f2bf(xv.v[r]);
                }
            } else {
#pragma unroll
                for (int r = 0; r < 4; ++r) {
                    int u = u0 + r;
                    u = (u < 0) ? -u : u;
                    u = (u >= LIN) ? (2 * (LIN - 1) - u) : u;
#pragma unroll
                    for (int j = 0; j < 8; ++j)
                        rows[r][j] = f2bf(base[(size_t)j * LIN_BASE + u]);
                }
            }
            short* dst = sx + (4 * t4) * ROWW + ci0;
            *(short8v*)(dst) = rows[0];
            *(short8v*)(dst + ROWW) = rows[1];
            *(short8v*)(dst + 2 * ROWW) = rows[2];
            *(short8v*)(dst + 3 * ROWW) = rows[3];
        }
    } else {
        // bf16 [n][t][c] staging with x2 linear upsample; contiguous row reads
        constexpr int CPR = CIN / 8;            // 16B chunks per row
        const short* inb = (const short*)in_ + (size_t)n * LIN_BASE * CIN;
        for (int uidx = tid; uidx < XT * CPR; uidx += 256) {
            int ci0 = (uidx % CPR) * 8;
            int t = uidx / CPR;
            int u = t0 - P + t;
            u = (u < 0) ? -u : u;
            u = (u >= LIN) ? (2 * (LIN - 1) - u) : u;
            int i = u >> 1;
            int ia, ib; float wa, wbw;
            if (u & 1) { ia = i; ib = (i + 1 < LIN_BASE) ? i + 1 : LIN_BASE - 1; wa = 0.75f; wbw = 0.25f; }
            else if (i == 0) { ia = 0; ib = 0; wa = 1.0f; wbw = 0.0f; }
            else { ia = i - 1; ib = i; wa = 0.25f; wbw = 0.75f; }
            short8v va = *(const short8v*)(inb + (size_t)ia * CIN + ci0);
            short8v vb = *(const short8v*)(inb + (size_t)ib * CIN + ci0);
            short8v pack;
#pragma unroll
            for (int j = 0; j < 8; ++j) {
                short sa = va[j], sb = vb[j];
                pack[j] = f2bf(wa * bf2f(sa) + wbw * bf2f(sb));
            }
            *(short8v*)(sx + t * ROWW + ci0) = pack;
        }
    }
    __syncthreads();

    const int wvi = tid >> 6;
    const int lane = tid & 63;
    const int ln = lane & 15;     // A: m=co row; B: n=t; D: col=t
    const int q = lane >> 4;      // k sub-block (q*8..q*8+7)
    const int tw = wvi * (TN * 16);

    float4v acc[WCOT][TN];
#pragma unroll
    for (int c = 0; c < WCOT; ++c)
#pragma unroll
        for (int j = 0; j < TN; ++j)
            acc[c][j] = (float4v){0.f, 0.f, 0.f, 0.f};

    const short* arow[WCOT];
#pragma unroll
    for (int c = 0; c < WCOT; ++c)
        arow[c] = wb + ((size_t)(c * 16 + ln)) * KPAD + q * 8;

    short8v acur[WCOT], anx[WCOT];
#pragma unroll
    for (int c = 0; c < WCOT; ++c)
        acur[c] = *(const short8v*)(arow[c]);

#pragma unroll 1
    for (int s = 0; s < NSTEP; ++s) {
        if (s + 1 < NSTEP) {
#pragma unroll
            for (int c = 0; c < WCOT; ++c)
                anx[c] = *(const short8v*)(arow[c] + (s + 1) * 32);
        }
        const int kk = s * 32 + q * 8;
        int tap = kk / CIN;                    // pow2 -> shift
        const int ci0 = kk & (CIN - 1);
        if constexpr (KPAD != K) {
            tap = (tap < K5) ? tap : (K5 - 1); // clamp addr for padded region
        }
        short8v b[TN];
#pragma unroll
        for (int j = 0; j < TN; ++j)
            b[j] = *(const short8v*)(sx + (tw + j * 16 + ln + tap * DIL) * ROWW + ci0);
        if constexpr (KPAD != K) {
            if (kk >= K) {
                short8v z = {0, 0, 0, 0, 0, 0, 0, 0};
#pragma unroll
                for (int j = 0; j < TN; ++j) b[j] = z;
            }
        }
#pragma unroll
        for (int c = 0; c < WCOT; ++c)
#pragma unroll
            for (int j = 0; j < TN; ++j)
                acc[c][j] = __builtin_amdgcn_mfma_f32_16x16x32_bf16(acur[c], b[j], acc[c][j], 0, 0, 0);
#pragma unroll
        for (int c = 0; c < WCOT; ++c)
            acur[c] = anx[c];
    }

    if constexpr (OUT_MODE == 0) {
        // bf16 [n][t][c]: lane holds 4 consecutive co -> one 8B store
        short* ob = (short*)out_ + ((size_t)n * LOUT + t0 + tw) * COUT;
#pragma unroll
        for (int c = 0; c < WCOT; ++c)
#pragma unroll
            for (int j = 0; j < TN; ++j) {
                if ((COUT % 16 == 0) || (q * 4 + 3 < COUT)) {
                    float4v v = acc[c][j];
                    short4v pk;
#pragma unroll
                    for (int r = 0; r < 4; ++r) {
                        int co = c * 16 + q * 4 + r;
                        float val = v[r] * ssc[co] + ssh[co];
                        if constexpr (HAS_BN) val = fmaxf(val, 0.f);
                        pk[r] = f2bf(val);
                    }
                    *(short4v*)(ob + (size_t)(j * 16 + ln) * COUT + c * 16 + q * 4) = pk;
                }
            }
    } else {
        // fp32 [n][c][t] (h4 -> up_loss)
        float* ob = (float*)out_ + (size_t)n * COUT * LOUT + t0 + tw + ln;
#pragma unroll
        for (int c = 0; c < WCOT; ++c)
#pragma unroll
            for (int j = 0; j < TN; ++j) {
                float4v v = acc[c][j];
#pragma unroll
                for (int r = 0; r < 4; ++r) {
                    int co = c * 16 + q * 4 + r;
                    if ((COUT % 16 == 0) || co < COUT) {
                        float val = v[r] * ssc[co] + ssh[co];
                        if constexpr (HAS_BN) val = fmaxf(val, 0.f);
                        ob[(size_t)co * LOUT + j * 16] = val;
                    }
                }
            }
    }
}

// ---- final upsample + transpose + loss --------------------------------------
__global__ __launch_bounds__(256) void up_loss_ker(
    const float* __restrict__ h4, const float* __restrict__ targets,
    float* __restrict__ out, float* __restrict__ loss_sum, int* __restrict__ flags)
{
    constexpr int L = 16384, LO = 32768;
    const int bt = blockIdx.x;
    const int t0 = blockIdx.y * 256;
    const int tid = threadIdx.x;
    const int i0 = t0 >> 1;

    __shared__ float sh[3 * 8 * 132];
    __shared__ int snz[8];
    __shared__ float swv[4];

    // stage 24 rows x 132 floats (i0-1 .. i0+130), float4-vectorized
    {
        const bool interior = (i0 >= 1) && (i0 + 130 <= L - 1);
        for (int idx = tid; idx < 24 * 33; idx += 256) {
            int row = idx / 33;
            int qd = idx - row * 33;
            int c = row >> 3, s = row & 7;
            int nn = bt * 8 + s;
            const float* src = h4 + ((size_t)nn * 3 + c) * L;
            int bi0 = i0 - 1 + 4 * qd;
            float4v v;
            if (interior) {
                v = ((const f4u*)(src + bi0))->v;
            } else {
#pragma unroll
                for (int k = 0; k < 4; ++k) {
                    int bi = bi0 + k;
                    bi = bi < 0 ? 0 : (bi > L - 1 ? L - 1 : bi);
                    v[k] = src[bi];
                }
            }
            *(float4v*)(sh + row * 132 + 4 * qd) = v;
        }
    }
    if (tid < 8) snz[tid] = 0;
    __syncthreads();

    const int tl = tid >> 1;            // 0..127 -> t offset
    const int st4 = (tid & 1) * 4;      // st half

    float lsum = 0.f;
    int nzm = 0;
#pragma unroll
    for (int rr = 0; rr < 2; ++rr) {
        int t = t0 + rr * 128 + tl;
        int li = (t >> 1) - i0 + 1;
        float o[3][4];
#pragma unroll
        for (int c = 0; c < 3; ++c)
#pragma unroll
            for (int s = 0; s < 4; ++s) {
                const float* row = sh + ((c << 3) + st4 + s) * 132;
                float v;
                if (t & 1) v = 0.75f * row[li] + 0.25f * row[li + 1];
                else       v = 0.25f * row[li - 1] + 0.75f * row[li];
                o[c][s] = v;
            }
        float tg[3][4];
#pragma unroll
        for (int c = 0; c < 3; ++c) {
            size_t obase = (((size_t)bt * 3 + c) * LO + t) * 8 + st4;
            float4v ov = { o[c][0], o[c][1], o[c][2], o[c][3] };
            *(float4v*)(out + obase) = ov;
            float4v tv = *(const float4v*)(targets + obase);
            tg[c][0] = tv[0]; tg[c][1] = tv[1]; tg[c][2] = tv[2]; tg[c][3] = tv[3];
        }
#pragma unroll
        for (int s = 0; s < 4; ++s) {
            float a0 = o[0][s], a1 = o[1][s], a2 = o[2][s];
            float mx = fmaxf(a0, fmaxf(a1, a2));
            float e0 = __expf(a0 - mx), e1 = __expf(a1 - mx), e2 = __expf(a2 - mx);
            float lse = mx + __logf(e0 + e1 + e2);
            lsum += tg[0][s] * (lse - a0) + tg[1][s] * (lse - a1) + tg[2][s] * (lse - a2);
            if ((tg[0][s] != 0.f) | (tg[1][s] != 0.f) | (tg[2][s] != 0.f)) nzm |= 1 << s;
        }
    }
    if (nzm) {
#pragma unroll
        for (int s = 0; s < 4; ++s) if (nzm & (1 << s)) snz[st4 + s] = 1;
    }

#pragma unroll
    for (int off = 32; off > 0; off >>= 1) lsum += __shfl_down(lsum, off, 64);
    if ((tid & 63) == 0) swv[tid >> 6] = lsum;
    __syncthreads();
    if (tid == 0) atomicAdd(loss_sum, swv[0] + swv[1] + swv[2] + swv[3]);
    if (tid < 8 && snz[tid]) atomicOr(&flags[bt * 8 + tid], 1);
}

__global__ __launch_bounds__(256) void finalize_ker(
    const int* __restrict__ flags, const float* __restrict__ loss_sum,
    float* __restrict__ out_loss)
{
    __shared__ int s[256];
    s[threadIdx.x] = flags[threadIdx.x] ? 1 : 0;
    __syncthreads();
    for (int off = 128; off > 0; off >>= 1) {
        if (threadIdx.x < off) s[threadIdx.x] += s[threadIdx.x + off];
        __syncthreads();
    }
    if (threadIdx.x == 0) out_loss[0] = loss_sum[0] / ((float)s[0] * 32768.0f);
}

extern "C" void kernel_launch(void* const* d_in, const int* in_sizes, int n_in,
                              void* d_out, int out_size, void* d_ws, size_t ws_size,
                              hipStream_t stream)
{
    const float* x  = (const float*)d_in[0];
    const float* tg = (const float*)d_in[1];
    const float* w0 = (const float*)d_in[2];
    const float* g0 = (const float*)d_in[3];
    const float* b0 = (const float*)d_in[4];
    const float* m0 = (const float*)d_in[5];
    const float* v0 = (const float*)d_in[6];
    const float* w1 = (const float*)d_in[7];
    const float* g1 = (const float*)d_in[8];
    const float* b1 = (const float*)d_in[9];
    const float* m1 = (const float*)d_in[10];
    const float* v1 = (const float*)d_in[11];
    const float* w2 = (const float*)d_in[12];
    const float* g2 = (const float*)d_in[13];
    const float* b2 = (const float*)d_in[14];
    const float* m2 = (const float*)d_in[15];
    const float* v2 = (const float*)d_in[16];
    const float* w3 = (const float*)d_in[17];
    const float* g3 = (const float*)d_in[18];
    const float* b3 = (const float*)d_in[19];
    const float* m3 = (const float*)d_in[20];
    const float* v3 = (const float*)d_in[21];
    const float* w_out = (const float*)d_in[22];
    const float* b_out = (const float*)d_in[23];
    float* outp = (float*)d_out;

    char* ws = (char*)d_ws;
    int* flags = (int*)ws;                           // [0,1024)
    float* loss_sum = (float*)(ws + 1024);
    short* wb0 = (short*)(ws + 4096);                // 64 x 640  = 81920 B
    short* wb1 = (short*)(ws + 86016);               // 32 x 320  = 20480 B
    short* wb2 = (short*)(ws + 106496);              // 16 x 160  =  5120 B
    short* wb3 = (short*)(ws + 111616);              // 16 x 96   =  3072 B
    short* wb4 = (short*)(ws + 114688);              // 16 x 64   =  2048 B
    const size_t BUF_OFF = 131072;
    const size_t BUFN = (size_t)16777216;            // floats per ping-pong buffer
    float* bufA = (float*)(ws + BUF_OFF);
    float* bufB = (ws_size >= BUF_OFF + 2 * BUFN * 4)
                      ? (bufA + BUFN)
                      : (float*)d_out;               // d_out as scratch fallback

    hipMemsetAsync(d_ws, 0, 4096, stream);

    wprep_all_ker<<<220, 256, 0, stream>>>(w0, w1, w2, w3, w_out,
                                           wb0, wb1, wb2, wb3, wb4);

    // h0 (256,64,1024)   fp32[c][t] -> bf16[t][c], T_TILE=128, ~36KB LDS
    conv_ker<128, 64, 1, 1024, 128, 4, true, 0, 0>
        <<<dim3(256, 8), 256, 0, stream>>>(x, wb0, g0, b0, m0, v0, bufA);
    // h1 (256,32,2048)   bf16[t][c] -> bf16[t][c], T_TILE=128, ~20KB LDS
    conv_ker<64, 32, 2, 2048, 128, 4, true, 1, 0>
        <<<dim3(256, 16), 256, 0, stream>>>(bufA, wb1, g1, b1, m1, v1, bufB);
    // h2 (256,16,4096)   T_TILE=256, ~22KB LDS
    conv_ker<32, 16, 4, 4096, 256, 4, true, 1, 0>
        <<<dim3(256, 16), 256, 0, stream>>>(bufB, wb2, g2, b2, m2, v2, bufA);
    // h3 (256,8,8192)    T_TILE=256, ~14KB LDS
    conv_ker<16, 8, 8, 8192, 256, 4, true, 1, 0>
        <<<dim3(256, 32), 256, 0, stream>>>(bufA, wb3, g3, b3, m3, v3, bufB);
    // h4 (256,3,16384)   bf16[t][c] -> fp32[c][t], T_TILE=256, ~10KB LDS
    conv_ker<8, 3, 16, 16384, 256, 4, false, 1, 1>
        <<<dim3(256, 64), 256, 0, stream>>>(bufB, wb4, b_out, b_out, b_out, b_out, bufA);
    // out + loss
    up_loss_ker<<<dim3(32, 128), 256, 0, stream>>>(bufA, tg, outp, loss_sum, flags);
    finalize_ker<<<1, 256, 0, stream>>>(flags, loss_sum, outp + (size_t)(out_size - 1));
}

// Round 4
// 511.025 us; speedup vs baseline: 1.2905x; 1.0992x over previous
//
#include <hip/hip_runtime.h>
#include <hip/hip_bf16.h>
#include <cstdint>
#include <cstddef>

#define K5 5
#define BNEPS 1e-5f

typedef __attribute__((ext_vector_type(8))) short short8v;
typedef __attribute__((ext_vector_type(4))) short short4v;
typedef __attribute__((ext_vector_type(4))) float float4v;

// 16B vector load with only 4B alignment guarantee
struct __attribute__((packed, aligned(4))) f4u { float4v v; };

__device__ inline float bf2f(short s) {
    __hip_bfloat16 h = *(__hip_bfloat16*)&s;
    return __bfloat162float(h);
}
__device__ inline short f2bf(float f) {
    __hip_bfloat16 h = __float2bfloat16(f);
    return *(short*)&h;
}

// ---- weight prep: fp32 [co][ci][tap] -> bf16 [co][kk], kk=tap*CIN+ci,
//      rows padded to MROWS (>=COUT) with zeros, k padded to KPAD with zeros.
template<int CIN, int COUT, int MROWS, int KPAD>
__device__ inline void wprep_body(const float* __restrict__ w,
                                  short* __restrict__ wb, int blk, int tid) {
    int idx = blk * 256 + tid;
    if (idx >= MROWS * KPAD) return;
    int co = idx / KPAD, kk = idx - co * KPAD;
    int tap = kk / CIN, ci = kk & (CIN - 1);
    float v = (co < COUT && tap < K5) ? w[((size_t)co * CIN + ci) * K5 + tap] : 0.f;
    wb[idx] = f2bf(v);
}

__global__ __launch_bounds__(256) void wprep_all_ker(
    const float* __restrict__ w0, const float* __restrict__ w1,
    const float* __restrict__ w2, const float* __restrict__ w3,
    const float* __restrict__ w4,
    short* __restrict__ wb0, short* __restrict__ wb1, short* __restrict__ wb2,
    short* __restrict__ wb3, short* __restrict__ wb4) {
    int b = blockIdx.x, t = threadIdx.x;
    if (b < 160)      wprep_body<128, 64, 64, 640>(w0, wb0, b, t);
    else if (b < 200) wprep_body<64, 32, 32, 320>(w1, wb1, b - 160, t);
    else if (b < 210) wprep_body<32, 16, 16, 160>(w2, wb2, b - 200, t);
    else if (b < 216) wprep_body<16, 8, 16, 96>(w3, wb3, b - 210, t);
    else              wprep_body<8, 3, 16, 64>(w4, wb4, b - 216, t);
}

// ---- MFMA conv, bf16 [n][t][c] activation layout ----------------------------
// GEMM D[co][t] = W[co][kk] * X[kk][t], kk = tap*CIN+ci.
// Waves: WCO co-groups x WT t-groups (WCO*WT = 4). WCO split halves per-wave
// redundant weight reads. A: full preload (NSTEP<=6) or depth-2 rolling
// prefetch. IN_MODE 0: fp32 [n][c][t] (h0). 1: bf16 [n][t][c] + x2 upsample.
// OUT_MODE 0: bf16 [n][t][c]. 1: fp32 [n][c][t] (h4 -> up_loss).
template<int CIN, int COUT, int DIL, int LOUT, int T_TILE, int WT, int WCO,
         bool HAS_BN, int IN_MODE, int OUT_MODE>
__global__ __launch_bounds__(256) void conv_ker(
    const void* __restrict__ in_, const short* __restrict__ wb,
    const float* __restrict__ gg, const float* __restrict__ bb,
    const float* __restrict__ mm, const float* __restrict__ vv,
    void* __restrict__ out_)
{
    constexpr int P = 2 * DIL;                  // ((K-1)*d+1)//2 == 2d
    constexpr int XT = T_TILE + 4 * DIL;
    constexpr int ROWW = (CIN == 8) ? 24 : (CIN + 8); // shorts; 16B mult, low-gcd bank stride
    constexpr int K = CIN * K5;
    constexpr int KPAD = ((K + 31) / 32) * 32;
    constexpr int NSTEP = KPAD / 32;
    constexpr int MT = (COUT + 15) / 16;        // total co tiles (zero-padded rows)
    constexpr int CT = MT / WCO;                // co tiles per wave
    constexpr int TN = T_TILE / (16 * WT);      // t-tiles per wave
    constexpr int LIN = LOUT;
    constexpr int LIN_BASE = (IN_MODE == 1) ? (LOUT / 2) : LOUT;
    static_assert(WT * WCO == 4, "4 waves");
    static_assert(MT % WCO == 0, "co split");
    static_assert(T_TILE % (16 * WT) == 0, "tile split");

    __shared__ short sx[XT * ROWW];
    __shared__ float ssc[COUT], ssh[COUT];

    const int n = blockIdx.x;
    const int t0 = blockIdx.y * T_TILE;
    const int tid = threadIdx.x;

    if (tid < COUT) {
        if constexpr (HAS_BN) {
            float inv = gg[tid] * rsqrtf(vv[tid] + BNEPS);
            ssc[tid] = inv;
            ssh[tid] = bb[tid] - mm[tid] * inv;
        } else {
            ssc[tid] = 1.f;
            ssh[tid] = bb[tid];
        }
    }

    if constexpr (IN_MODE == 0) {
        // fp32 [n][c][t] staging, 4-t vectorized spans (no upsample)
        static_assert(XT % 4 == 0, "XT mult of 4");
        constexpr int T4 = XT / 4;
        constexpr int NITEM = T4 * (CIN / 8);
        const float* in = (const float*)in_;
        for (int uidx = tid; uidx < NITEM; uidx += 256) {
            int t4 = uidx % T4;
            int ci0 = (uidx / T4) * 8;
            const int u0 = t0 - P + 4 * t4;
            const float* base = in + ((size_t)n * CIN + ci0) * LIN_BASE;
            short8v rows[4];
            bool fast = (u0 >= 0) && (u0 + 3 <= LIN - 1);
            if (fast) {
#pragma unroll
                for (int j = 0; j < 8; ++j) {
                    f4u xv = *(const f4u*)(base + (size_t)j * LIN_BASE + u0);
#pragma unroll
                    for (int r = 0; r < 4; ++r) rows[r][j] = f2bf(xv.v[r]);
                }
            } else {
#pragma unroll
                for (int r = 0; r < 4; ++r) {
                    int u = u0 + r;
                    u = (u < 0) ? -u : u;
                    u = (u >= LIN) ? (2 * (LIN - 1) - u) : u;
#pragma unroll
                    for (int j = 0; j < 8; ++j)
                        rows[r][j] = f2bf(base[(size_t)j * LIN_BASE + u]);
                }
            }
            short* dst = sx + (4 * t4) * ROWW + ci0;
            *(short8v*)(dst) = rows[0];
            *(short8v*)(dst + ROWW) = rows[1];
            *(short8v*)(dst + 2 * ROWW) = rows[2];
            *(short8v*)(dst + 3 * ROWW) = rows[3];
        }
    } else {
        // bf16 [n][t][c] staging with x2 linear upsample; contiguous row reads
        constexpr int CPR = CIN / 8;            // 16B chunks per row
        const short* inb = (const short*)in_ + (size_t)n * LIN_BASE * CIN;
        for (int uidx = tid; uidx < XT * CPR; uidx += 256) {
            int ci0 = (uidx % CPR) * 8;
            int t = uidx / CPR;
            int u = t0 - P + t;
            u = (u < 0) ? -u : u;
            u = (u >= LIN) ? (2 * (LIN - 1) - u) : u;
            int i = u >> 1;
            int ia, ib; float wa, wbw;
            if (u & 1) { ia = i; ib = (i + 1 < LIN_BASE) ? i + 1 : LIN_BASE - 1; wa = 0.75f; wbw = 0.25f; }
            else if (i == 0) { ia = 0; ib = 0; wa = 1.0f; wbw = 0.0f; }
            else { ia = i - 1; ib = i; wa = 0.25f; wbw = 0.75f; }
            short8v va = *(const short8v*)(inb + (size_t)ia * CIN + ci0);
            short8v vb = *(const short8v*)(inb + (size_t)ib * CIN + ci0);
            short8v pack;
#pragma unroll
            for (int j = 0; j < 8; ++j) {
                short sa = va[j], sb = vb[j];
                pack[j] = f2bf(wa * bf2f(sa) + wbw * bf2f(sb));
            }
            *(short8v*)(sx + t * ROWW + ci0) = pack;
        }
    }
    __syncthreads();

    const int wvi = tid >> 6;
    const int lane = tid & 63;
    const int ln = lane & 15;     // A: m=co row; B: n=t; D: col=t
    const int q = lane >> 4;      // k sub-block (q*8..q*8+7)
    const int tg = wvi % WT;
    const int cg = wvi / WT;
    const int tw = tg * (TN * 16);

    float4v acc[CT][TN];
#pragma unroll
    for (int c = 0; c < CT; ++c)
#pragma unroll
        for (int j = 0; j < TN; ++j)
            acc[c][j] = (float4v){0.f, 0.f, 0.f, 0.f};

    const short* arow[CT];
#pragma unroll
    for (int c = 0; c < CT; ++c)
        arow[c] = wb + ((size_t)((cg * CT + c) * 16 + ln)) * KPAD + q * 8;

    if constexpr (NSTEP <= 6) {
        // full A preload: K-loop has zero global loads
        short8v aall[NSTEP][CT];
#pragma unroll
        for (int s = 0; s < NSTEP; ++s)
#pragma unroll
            for (int c = 0; c < CT; ++c)
                aall[s][c] = *(const short8v*)(arow[c] + s * 32);
#pragma unroll
        for (int s = 0; s < NSTEP; ++s) {
            const int kk = s * 32 + q * 8;
            int tap = kk / CIN;
            const int ci0 = kk & (CIN - 1);
            if constexpr (KPAD != K) {
                tap = (tap < K5) ? tap : (K5 - 1);
            }
            short8v b[TN];
#pragma unroll
            for (int j = 0; j < TN; ++j)
                b[j] = *(const short8v*)(sx + (tw + j * 16 + ln + tap * DIL) * ROWW + ci0);
            if constexpr (KPAD != K) {
                if (kk >= K) {
                    short8v z = {0, 0, 0, 0, 0, 0, 0, 0};
#pragma unroll
                    for (int j = 0; j < TN; ++j) b[j] = z;
                }
            }
#pragma unroll
            for (int c = 0; c < CT; ++c)
#pragma unroll
                for (int j = 0; j < TN; ++j)
                    acc[c][j] = __builtin_amdgcn_mfma_f32_16x16x32_bf16(aall[s][c], b[j], acc[c][j], 0, 0, 0);
        }
    } else {
        // depth-2 rolling prefetch
        short8v a0[CT], a1[CT], a2[CT];
#pragma unroll
        for (int c = 0; c < CT; ++c) a0[c] = *(const short8v*)(arow[c]);
#pragma unroll
        for (int c = 0; c < CT; ++c) a1[c] = *(const short8v*)(arow[c] + 32);
#pragma unroll 1
        for (int s = 0; s < NSTEP; ++s) {
            if (s + 2 < NSTEP) {
#pragma unroll
                for (int c = 0; c < CT; ++c)
                    a2[c] = *(const short8v*)(arow[c] + (s + 2) * 32);
            }
            const int kk = s * 32 + q * 8;
            int tap = kk / CIN;
            const int ci0 = kk & (CIN - 1);
            if constexpr (KPAD != K) {
                tap = (tap < K5) ? tap : (K5 - 1);
            }
            short8v b[TN];
#pragma unroll
            for (int j = 0; j < TN; ++j)
                b[j] = *(const short8v*)(sx + (tw + j * 16 + ln + tap * DIL) * ROWW + ci0);
            if constexpr (KPAD != K) {
                if (kk >= K) {
                    short8v z = {0, 0, 0, 0, 0, 0, 0, 0};
#pragma unroll
                    for (int j = 0; j < TN; ++j) b[j] = z;
                }
            }
#pragma unroll
            for (int c = 0; c < CT; ++c)
#pragma unroll
                for (int j = 0; j < TN; ++j)
                    acc[c][j] = __builtin_amdgcn_mfma_f32_16x16x32_bf16(a0[c], b[j], acc[c][j], 0, 0, 0);
#pragma unroll
            for (int c = 0; c < CT; ++c) { a0[c] = a1[c]; a1[c] = a2[c]; }
        }
    }

    if constexpr (OUT_MODE == 0) {
        // bf16 [n][t][c]: lane holds 4 consecutive co -> one 8B store
        short* ob = (short*)out_ + ((size_t)n * LOUT + t0 + tw) * COUT;
#pragma unroll
        for (int c = 0; c < CT; ++c)
#pragma unroll
            for (int j = 0; j < TN; ++j) {
                if ((COUT % 16 == 0) || (q * 4 + 3 < COUT)) {
                    float4v v = acc[c][j];
                    short4v pk;
#pragma unroll
                    for (int r = 0; r < 4; ++r) {
                        int co = (cg * CT + c) * 16 + q * 4 + r;
                        float val = v[r] * ssc[co] + ssh[co];
                        if constexpr (HAS_BN) val = fmaxf(val, 0.f);
                        pk[r] = f2bf(val);
                    }
                    *(short4v*)(ob + (size_t)(j * 16 + ln) * COUT + (cg * CT + c) * 16 + q * 4) = pk;
                }
            }
    } else {
        // fp32 [n][c][t] (h4 -> up_loss)
        float* ob = (float*)out_ + (size_t)n * COUT * LOUT + t0 + tw + ln;
#pragma unroll
        for (int c = 0; c < CT; ++c)
#pragma unroll
            for (int j = 0; j < TN; ++j) {
                float4v v = acc[c][j];
#pragma unroll
                for (int r = 0; r < 4; ++r) {
                    int co = (cg * CT + c) * 16 + q * 4 + r;
                    if ((COUT % 16 == 0) || co < COUT) {
                        float val = v[r] * ssc[co] + ssh[co];
                        if constexpr (HAS_BN) val = fmaxf(val, 0.f);
                        ob[(size_t)co * LOUT + j * 16] = val;
                    }
                }
            }
    }
}

// ---- final upsample + transpose + loss --------------------------------------
__global__ __launch_bounds__(256) void up_loss_ker(
    const float* __restrict__ h4, const float* __restrict__ targets,
    float* __restrict__ out, float* __restrict__ loss_sum, int* __restrict__ flags)
{
    constexpr int L = 16384, LO = 32768;
    const int bt = blockIdx.x;
    const int t0 = blockIdx.y * 256;
    const int tid = threadIdx.x;
    const int i0 = t0 >> 1;

    __shared__ float sh[3 * 8 * 132];
    __shared__ int snz[8];
    __shared__ float swv[4];

    // stage 24 rows x 132 floats (i0-1 .. i0+130), float4-vectorized
    {
        const bool interior = (i0 >= 1) && (i0 + 130 <= L - 1);
        for (int idx = tid; idx < 24 * 33; idx += 256) {
            int row = idx / 33;
            int qd = idx - row * 33;
            int c = row >> 3, s = row & 7;
            int nn = bt * 8 + s;
            const float* src = h4 + ((size_t)nn * 3 + c) * L;
            int bi0 = i0 - 1 + 4 * qd;
            float4v v;
            if (interior) {
                v = ((const f4u*)(src + bi0))->v;
            } else {
#pragma unroll
                for (int k = 0; k < 4; ++k) {
                    int bi = bi0 + k;
                    bi = bi < 0 ? 0 : (bi > L - 1 ? L - 1 : bi);
                    v[k] = src[bi];
                }
            }
            *(float4v*)(sh + row * 132 + 4 * qd) = v;
        }
    }
    if (tid < 8) snz[tid] = 0;
    __syncthreads();

    const int tl = tid >> 1;            // 0..127 -> t offset
    const int st4 = (tid & 1) * 4;      // st half

    float lsum = 0.f;
    int nzm = 0;
#pragma unroll
    for (int rr = 0; rr < 2; ++rr) {
        int t = t0 + rr * 128 + tl;
        int li = (t >> 1) - i0 + 1;
        float o[3][4];
#pragma unroll
        for (int c = 0; c < 3; ++c)
#pragma unroll
            for (int s = 0; s < 4; ++s) {
                const float* row = sh + ((c << 3) + st4 + s) * 132;
                float v;
                if (t & 1) v = 0.75f * row[li] + 0.25f * row[li + 1];
                else       v = 0.25f * row[li - 1] + 0.75f * row[li];
                o[c][s] = v;
            }
        float tg[3][4];
#pragma unroll
        for (int c = 0; c < 3; ++c) {
            size_t obase = (((size_t)bt * 3 + c) * LO + t) * 8 + st4;
            float4v ov = { o[c][0], o[c][1], o[c][2], o[c][3] };
            *(float4v*)(out + obase) = ov;
            float4v tv = *(const float4v*)(targets + obase);
            tg[c][0] = tv[0]; tg[c][1] = tv[1]; tg[c][2] = tv[2]; tg[c][3] = tv[3];
        }
#pragma unroll
        for (int s = 0; s < 4; ++s) {
            float a0 = o[0][s], a1 = o[1][s], a2 = o[2][s];
            float mx = fmaxf(a0, fmaxf(a1, a2));
            float e0 = __expf(a0 - mx), e1 = __expf(a1 - mx), e2 = __expf(a2 - mx);
            float lse = mx + __logf(e0 + e1 + e2);
            lsum += tg[0][s] * (lse - a0) + tg[1][s] * (lse - a1) + tg[2][s] * (lse - a2);
            if ((tg[0][s] != 0.f) | (tg[1][s] != 0.f) | (tg[2][s] != 0.f)) nzm |= 1 << s;
        }
    }
    if (nzm) {
#pragma unroll
        for (int s = 0; s < 4; ++s) if (nzm & (1 << s)) snz[st4 + s] = 1;
    }

#pragma unroll
    for (int off = 32; off > 0; off >>= 1) lsum += __shfl_down(lsum, off, 64);
    if ((tid & 63) == 0) swv[tid >> 6] = lsum;
    __syncthreads();
    if (tid == 0) atomicAdd(loss_sum, swv[0] + swv[1] + swv[2] + swv[3]);
    if (tid < 8 && snz[tid]) atomicOr(&flags[bt * 8 + tid], 1);
}

__global__ __launch_bounds__(256) void finalize_ker(
    const int* __restrict__ flags, const float* __restrict__ loss_sum,
    float* __restrict__ out_loss)
{
    __shared__ int s[256];
    s[threadIdx.x] = flags[threadIdx.x] ? 1 : 0;
    __syncthreads();
    for (int off = 128; off > 0; off >>= 1) {
        if (threadIdx.x < off) s[threadIdx.x] += s[threadIdx.x + off];
        __syncthreads();
    }
    if (threadIdx.x == 0) out_loss[0] = loss_sum[0] / ((float)s[0] * 32768.0f);
}

extern "C" void kernel_launch(void* const* d_in, const int* in_sizes, int n_in,
                              void* d_out, int out_size, void* d_ws, size_t ws_size,
                              hipStream_t stream)
{
    const float* x  = (const float*)d_in[0];
    const float* tg = (const float*)d_in[1];
    const float* w0 = (const float*)d_in[2];
    const float* g0 = (const float*)d_in[3];
    const float* b0 = (const float*)d_in[4];
    const float* m0 = (const float*)d_in[5];
    const float* v0 = (const float*)d_in[6];
    const float* w1 = (const float*)d_in[7];
    const float* g1 = (const float*)d_in[8];
    const float* b1 = (const float*)d_in[9];
    const float* m1 = (const float*)d_in[10];
    const float* v1 = (const float*)d_in[11];
    const float* w2 = (const float*)d_in[12];
    const float* g2 = (const float*)d_in[13];
    const float* b2 = (const float*)d_in[14];
    const float* m2 = (const float*)d_in[15];
    const float* v2 = (const float*)d_in[16];
    const float* w3 = (const float*)d_in[17];
    const float* g3 = (const float*)d_in[18];
    const float* b3 = (const float*)d_in[19];
    const float* m3 = (const float*)d_in[20];
    const float* v3 = (const float*)d_in[21];
    const float* w_out = (const float*)d_in[22];
    const float* b_out = (const float*)d_in[23];
    float* outp = (float*)d_out;

    char* ws = (char*)d_ws;
    int* flags = (int*)ws;                           // [0,1024)
    float* loss_sum = (float*)(ws + 1024);
    short* wb0 = (short*)(ws + 4096);                // 64 x 640  = 81920 B
    short* wb1 = (short*)(ws + 86016);               // 32 x 320  = 20480 B
    short* wb2 = (short*)(ws + 106496);              // 16 x 160  =  5120 B
    short* wb3 = (short*)(ws + 111616);              // 16 x 96   =  3072 B
    short* wb4 = (short*)(ws + 114688);              // 16 x 64   =  2048 B
    const size_t BUF_OFF = 131072;
    const size_t BUFN = (size_t)16777216;            // floats per ping-pong buffer
    float* bufA = (float*)(ws + BUF_OFF);
    float* bufB = (ws_size >= BUF_OFF + 2 * BUFN * 4)
                      ? (bufA + BUFN)
                      : (float*)d_out;               // d_out as scratch fallback

    hipMemsetAsync(d_ws, 0, 4096, stream);

    wprep_all_ker<<<220, 256, 0, stream>>>(w0, w1, w2, w3, w_out,
                                           wb0, wb1, wb2, wb3, wb4);

    // h0 (256,64,1024)  fp32[c][t]->bf16[t][c], T=128, WT=2/WCO=2, 36KB LDS
    conv_ker<128, 64, 1, 1024, 128, 2, 2, true, 0, 0>
        <<<dim3(256, 8), 256, 0, stream>>>(x, wb0, g0, b0, m0, v0, bufA);
    // h1 (256,32,2048)  T=256, WT=2/WCO=2, 38KB LDS
    conv_ker<64, 32, 2, 2048, 256, 2, 2, true, 1, 0>
        <<<dim3(256, 8), 256, 0, stream>>>(bufA, wb1, g1, b1, m1, v1, bufB);
    // h2 (256,16,4096)  T=512, WT=4/WCO=1, 42KB LDS, full A-preload
    conv_ker<32, 16, 4, 4096, 512, 4, 1, true, 1, 0>
        <<<dim3(256, 8), 256, 0, stream>>>(bufB, wb2, g2, b2, m2, v2, bufA);
    // h3 (256,8,8192)   T=512, WT=4/WCO=1, 26KB LDS, full A-preload
    conv_ker<16, 8, 8, 8192, 512, 4, 1, true, 1, 0>
        <<<dim3(256, 16), 256, 0, stream>>>(bufA, wb3, g3, b3, m3, v3, bufB);
    // h4 (256,3,16384)  T=512, WT=4/WCO=1, 28KB LDS, full A-preload
    conv_ker<8, 3, 16, 16384, 512, 4, 1, false, 1, 1>
        <<<dim3(256, 32), 256, 0, stream>>>(bufB, wb4, b_out, b_out, b_out, b_out, bufA);
    // out + loss
    up_loss_ker<<<dim3(32, 128), 256, 0, stream>>>(bufA, tg, outp, loss_sum, flags);
    finalize_ker<<<1, 256, 0, stream>>>(flags, loss_sum, outp + (size_t)(out_size - 1));
}

// Round 5
// 505.794 us; speedup vs baseline: 1.3038x; 1.0103x over previous
//
#include <hip/hip_runtime.h>
#include <hip/hip_bf16.h>
#include <cstdint>
#include <cstddef>

#define K5 5
#define BNEPS 1e-5f

typedef __attribute__((ext_vector_type(8))) short short8v;
typedef __attribute__((ext_vector_type(4))) short short4v;
typedef __attribute__((ext_vector_type(4))) float float4v;

// 16B vector load with only 4B alignment guarantee
struct __attribute__((packed, aligned(4))) f4u { float4v v; };

__device__ inline float bf2f(short s) {
    __hip_bfloat16 h = *(__hip_bfloat16*)&s;
    return __bfloat162float(h);
}
__device__ inline short f2bf(float f) {
    __hip_bfloat16 h = __float2bfloat16(f);
    return *(short*)&h;
}

// ---- weight prep: fp32 [co][ci][tap] -> bf16 [co][kk], kk=tap*CIN+ci,
//      rows padded to MROWS (>=COUT) with zeros, k padded to KPAD with zeros.
template<int CIN, int COUT, int MROWS, int KPAD>
__device__ inline void wprep_body(const float* __restrict__ w,
                                  short* __restrict__ wb, int blk, int tid) {
    int idx = blk * 256 + tid;
    if (idx >= MROWS * KPAD) return;
    int co = idx / KPAD, kk = idx - co * KPAD;
    int tap = kk / CIN, ci = kk & (CIN - 1);
    float v = (co < COUT && tap < K5) ? w[((size_t)co * CIN + ci) * K5 + tap] : 0.f;
    wb[idx] = f2bf(v);
}

__global__ __launch_bounds__(256) void wprep_all_ker(
    const float* __restrict__ w0, const float* __restrict__ w1,
    const float* __restrict__ w2, const float* __restrict__ w3,
    const float* __restrict__ w4,
    short* __restrict__ wb0, short* __restrict__ wb1, short* __restrict__ wb2,
    short* __restrict__ wb3, short* __restrict__ wb4) {
    int b = blockIdx.x, t = threadIdx.x;
    if (b < 160)      wprep_body<128, 64, 64, 640>(w0, wb0, b, t);
    else if (b < 200) wprep_body<64, 32, 32, 320>(w1, wb1, b - 160, t);
    else if (b < 210) wprep_body<32, 16, 16, 160>(w2, wb2, b - 200, t);
    else if (b < 216) wprep_body<16, 8, 16, 96>(w3, wb3, b - 210, t);
    else              wprep_body<8, 3, 16, 64>(w4, wb4, b - 216, t);
}

// ---- MFMA conv, bf16 [n][t][c] activation layout ----------------------------
// GEMM D[co][t] = W[co][kk] * X[kk][t], kk = tap*CIN+ci.
// Waves: WCO co-groups x WT t-groups. Stage paths are load-batched (8-16
// independent global loads in flight before any use) and sx uses a 16B-chunk
// XOR swizzle (chunk ^ (row>>2)) to kill stage ds_write bank conflicts.
// IN_MODE 0: fp32 [n][c][t] (h0). 1: bf16 [n][t][c] + x2 upsample.
// OUT_MODE 0: bf16 [n][t][c]. 1: fp32 [n][c][t] (h4 -> up_loss).
template<int CIN, int COUT, int DIL, int LOUT, int T_TILE, int WT, int WCO,
         bool HAS_BN, int IN_MODE, int OUT_MODE>
__global__ __launch_bounds__(256) void conv_ker(
    const void* __restrict__ in_, const short* __restrict__ wb,
    const float* __restrict__ gg, const float* __restrict__ bb,
    const float* __restrict__ mm, const float* __restrict__ vv,
    void* __restrict__ out_)
{
    constexpr int P = 2 * DIL;                  // ((K-1)*d+1)//2 == 2d
    constexpr int XT = T_TILE + 4 * DIL;
    constexpr int ROWW = (CIN == 8) ? 24 : (CIN + 8); // shorts; 16B mult rows
    constexpr int CPR = CIN / 8;                // 16B chunks per row (pow2)
    constexpr int K = CIN * K5;
    constexpr int KPAD = ((K + 31) / 32) * 32;
    constexpr int NSTEP = KPAD / 32;
    constexpr int MT = (COUT + 15) / 16;        // total co tiles
    constexpr int CT = MT / WCO;                // co tiles per wave
    constexpr int TN = T_TILE / (16 * WT);      // t-tiles per wave
    constexpr int LIN = LOUT;
    constexpr int LIN_BASE = (IN_MODE == 1) ? (LOUT / 2) : LOUT;
    static_assert(WT * WCO == 4, "4 waves");
    static_assert(MT % WCO == 0, "co split");
    static_assert(T_TILE % (16 * WT) == 0, "tile split");

    __shared__ short sx[XT * ROWW];
    __shared__ float ssc[COUT], ssh[COUT];

    const int n = blockIdx.x;
    const int t0 = blockIdx.y * T_TILE;
    const int tid = threadIdx.x;

    // 16B-chunk XOR swizzle: bijective within each row; identical on all
    // sx reads/writes (all are chunk-aligned 16B accesses).
    auto swzoff = [](int row, int c) -> int {
        int pc = c ^ ((row >> 2) & (CPR - 1));
        return row * ROWW + (pc << 3);
    };

    if (tid < COUT) {
        if constexpr (HAS_BN) {
            float inv = gg[tid] * rsqrtf(vv[tid] + BNEPS);
            ssc[tid] = inv;
            ssh[tid] = bb[tid] - mm[tid] * inv;
        } else {
            ssc[tid] = 1.f;
            ssh[tid] = bb[tid];
        }
    }

    if constexpr (IN_MODE == 0) {
        // fp32 [n][c][t] staging, 4-t vectorized spans, batched 2 items deep
        static_assert(XT % 4 == 0, "XT mult of 4");
        constexpr int T4 = XT / 4;
        constexpr int NITEM = T4 * CPR;
        constexpr int U0 = 2;
        const float* in = (const float*)in_;
        for (int base = tid; base < NITEM; base += 256 * U0) {
            f4u xv[U0][8];
            int t4s[U0], ci0s[U0], u0s[U0];
            bool fasts[U0], vals[U0];
#pragma unroll
            for (int u = 0; u < U0; ++u) {
                int idx = base + u * 256;
                vals[u] = idx < NITEM;
                int id2 = vals[u] ? idx : 0;
                int t4 = id2 % T4;
                int ci0 = (id2 / T4) * 8;
                int u0 = t0 - P + 4 * t4;
                bool fast = (u0 >= 0) && (u0 + 3 <= LIN - 1);
                int uc = u0 < 0 ? 0 : (u0 > LIN - 4 ? LIN - 4 : u0);
                const float* basep = in + ((size_t)n * CIN + ci0) * LIN_BASE;
#pragma unroll
                for (int j = 0; j < 8; ++j)
                    xv[u][j] = *(const f4u*)(basep + (size_t)j * LIN_BASE + uc);
                t4s[u] = t4; ci0s[u] = ci0; u0s[u] = u0; fasts[u] = fast;
            }
#pragma unroll
            for (int u = 0; u < U0; ++u) {
                if (!vals[u]) continue;
                short8v rows[4];
                if (fasts[u]) {
#pragma unroll
                    for (int j = 0; j < 8; ++j)
#pragma unroll
                        for (int r = 0; r < 4; ++r)
                            rows[r][j] = f2bf(xv[u][j].v[r]);
                } else {
                    const float* basep = in + ((size_t)n * CIN + ci0s[u]) * LIN_BASE;
#pragma unroll
                    for (int r = 0; r < 4; ++r) {
                        int uu = u0s[u] + r;
                        uu = (uu < 0) ? -uu : uu;
                        uu = (uu >= LIN) ? (2 * (LIN - 1) - uu) : uu;
#pragma unroll
                        for (int j = 0; j < 8; ++j)
                            rows[r][j] = f2bf(basep[(size_t)j * LIN_BASE + uu]);
                    }
                }
                int cc = ci0s[u] >> 3;
#pragma unroll
                for (int r = 0; r < 4; ++r)
                    *(short8v*)(sx + swzoff(4 * t4s[u] + r, cc)) = rows[r];
            }
        }
    } else {
        // bf16 [n][t][c] staging with x2 upsample; batched 4 items deep
        constexpr int ITEMS = XT * CPR;
        constexpr int UU = 4;
        const short* inb = (const short*)in_ + (size_t)n * LIN_BASE * CIN;
        for (int base = tid; base < ITEMS; base += 256 * UU) {
            short8v va[UU], vb[UU];
            float wav[UU], wbv[UU];
            int trow[UU], cc[UU];
            bool vals[UU];
#pragma unroll
            for (int u = 0; u < UU; ++u) {
                int idx = base + u * 256;
                vals[u] = idx < ITEMS;
                int id2 = vals[u] ? idx : 0;
                int ci0 = (id2 % CPR) * 8;
                int t = id2 / CPR;
                int uu2 = t0 - P + t;
                uu2 = (uu2 < 0) ? -uu2 : uu2;
                uu2 = (uu2 >= LIN) ? (2 * (LIN - 1) - uu2) : uu2;
                int i = uu2 >> 1;
                int ia, ib; float wa, wbw;
                if (uu2 & 1) { ia = i; ib = (i + 1 < LIN_BASE) ? i + 1 : LIN_BASE - 1; wa = 0.75f; wbw = 0.25f; }
                else if (i == 0) { ia = 0; ib = 0; wa = 1.0f; wbw = 0.0f; }
                else { ia = i - 1; ib = i; wa = 0.25f; wbw = 0.75f; }
                va[u] = *(const short8v*)(inb + (size_t)ia * CIN + ci0);
                vb[u] = *(const short8v*)(inb + (size_t)ib * CIN + ci0);
                wav[u] = wa; wbv[u] = wbw; trow[u] = t; cc[u] = ci0 >> 3;
            }
#pragma unroll
            for (int u = 0; u < UU; ++u) {
                if (!vals[u]) continue;
                short8v pack;
#pragma unroll
                for (int j = 0; j < 8; ++j)
                    pack[j] = f2bf(wav[u] * bf2f(va[u][j]) + wbv[u] * bf2f(vb[u][j]));
                *(short8v*)(sx + swzoff(trow[u], cc[u])) = pack;
            }
        }
    }
    __syncthreads();

    const int wvi = tid >> 6;
    const int lane = tid & 63;
    const int ln = lane & 15;     // A: m=co row; B: n=t; D: col=t
    const int q = lane >> 4;      // k sub-block (q*8..q*8+7)
    const int tg = wvi % WT;
    const int cg = wvi / WT;
    const int tw = tg * (TN * 16);

    float4v acc[CT][TN];
#pragma unroll
    for (int c = 0; c < CT; ++c)
#pragma unroll
        for (int j = 0; j < TN; ++j)
            acc[c][j] = (float4v){0.f, 0.f, 0.f, 0.f};

    const short* arow[CT];
#pragma unroll
    for (int c = 0; c < CT; ++c)
        arow[c] = wb + ((size_t)((cg * CT + c) * 16 + ln)) * KPAD + q * 8;

    if constexpr (NSTEP <= 6) {
        // full A preload: K-loop has zero global loads
        short8v aall[NSTEP][CT];
#pragma unroll
        for (int s = 0; s < NSTEP; ++s)
#pragma unroll
            for (int c = 0; c < CT; ++c)
                aall[s][c] = *(const short8v*)(arow[c] + s * 32);
#pragma unroll
        for (int s = 0; s < NSTEP; ++s) {
            const int kk = s * 32 + q * 8;
            int tap = kk / CIN;
            const int ci0 = kk & (CIN - 1);
            if constexpr (KPAD != K) {
                tap = (tap < K5) ? tap : (K5 - 1);
            }
            short8v b[TN];
#pragma unroll
            for (int j = 0; j < TN; ++j)
                b[j] = *(const short8v*)(sx + swzoff(tw + j * 16 + ln + tap * DIL, ci0 >> 3));
            if constexpr (KPAD != K) {
                if (kk >= K) {
                    short8v z = {0, 0, 0, 0, 0, 0, 0, 0};
#pragma unroll
                    for (int j = 0; j < TN; ++j) b[j] = z;
                }
            }
#pragma unroll
            for (int c = 0; c < CT; ++c)
#pragma unroll
                for (int j = 0; j < TN; ++j)
                    acc[c][j] = __builtin_amdgcn_mfma_f32_16x16x32_bf16(aall[s][c], b[j], acc[c][j], 0, 0, 0);
        }
    } else {
        // depth-2 rolling prefetch
        short8v a0[CT], a1[CT], a2[CT];
#pragma unroll
        for (int c = 0; c < CT; ++c) a0[c] = *(const short8v*)(arow[c]);
#pragma unroll
        for (int c = 0; c < CT; ++c) a1[c] = *(const short8v*)(arow[c] + 32);
#pragma unroll 1
        for (int s = 0; s < NSTEP; ++s) {
            if (s + 2 < NSTEP) {
#pragma unroll
                for (int c = 0; c < CT; ++c)
                    a2[c] = *(const short8v*)(arow[c] + (s + 2) * 32);
            }
            const int kk = s * 32 + q * 8;
            int tap = kk / CIN;
            const int ci0 = kk & (CIN - 1);
            if constexpr (KPAD != K) {
                tap = (tap < K5) ? tap : (K5 - 1);
            }
            short8v b[TN];
#pragma unroll
            for (int j = 0; j < TN; ++j)
                b[j] = *(const short8v*)(sx + swzoff(tw + j * 16 + ln + tap * DIL, ci0 >> 3));
            if constexpr (KPAD != K) {
                if (kk >= K) {
                    short8v z = {0, 0, 0, 0, 0, 0, 0, 0};
#pragma unroll
                    for (int j = 0; j < TN; ++j) b[j] = z;
                }
            }
#pragma unroll
            for (int c = 0; c < CT; ++c)
#pragma unroll
                for (int j = 0; j < TN; ++j)
                    acc[c][j] = __builtin_amdgcn_mfma_f32_16x16x32_bf16(a0[c], b[j], acc[c][j], 0, 0, 0);
#pragma unroll
            for (int c = 0; c < CT; ++c) { a0[c] = a1[c]; a1[c] = a2[c]; }
        }
    }

    if constexpr (OUT_MODE == 0) {
        // bf16 [n][t][c]: lane holds 4 consecutive co -> one 8B store
        short* ob = (short*)out_ + ((size_t)n * LOUT + t0 + tw) * COUT;
#pragma unroll
        for (int c = 0; c < CT; ++c)
#pragma unroll
            for (int j = 0; j < TN; ++j) {
                if ((COUT % 16 == 0) || (q * 4 + 3 < COUT)) {
                    float4v v = acc[c][j];
                    short4v pk;
#pragma unroll
                    for (int r = 0; r < 4; ++r) {
                        int co = (cg * CT + c) * 16 + q * 4 + r;
                        float val = v[r] * ssc[co] + ssh[co];
                        if constexpr (HAS_BN) val = fmaxf(val, 0.f);
                        pk[r] = f2bf(val);
                    }
                    *(short4v*)(ob + (size_t)(j * 16 + ln) * COUT + (cg * CT + c) * 16 + q * 4) = pk;
                }
            }
    } else {
        // fp32 [n][c][t] (h4 -> up_loss)
        float* ob = (float*)out_ + (size_t)n * COUT * LOUT + t0 + tw + ln;
#pragma unroll
        for (int c = 0; c < CT; ++c)
#pragma unroll
            for (int j = 0; j < TN; ++j) {
                float4v v = acc[c][j];
#pragma unroll
                for (int r = 0; r < 4; ++r) {
                    int co = (cg * CT + c) * 16 + q * 4 + r;
                    if ((COUT % 16 == 0) || co < COUT) {
                        float val = v[r] * ssc[co] + ssh[co];
                        if constexpr (HAS_BN) val = fmaxf(val, 0.f);
                        ob[(size_t)co * LOUT + j * 16] = val;
                    }
                }
            }
    }
}

// ---- final upsample + transpose + loss --------------------------------------
__global__ __launch_bounds__(256) void up_loss_ker(
    const float* __restrict__ h4, const float* __restrict__ targets,
    float* __restrict__ out, float* __restrict__ loss_sum, int* __restrict__ flags)
{
    constexpr int L = 16384, LO = 32768;
    const int bt = blockIdx.x;
    const int t0 = blockIdx.y * 256;
    const int tid = threadIdx.x;
    const int i0 = t0 >> 1;

    __shared__ float sh[3 * 8 * 132];
    __shared__ int snz[8];
    __shared__ float swv[4];

    const int tl = tid >> 1;            // 0..127 -> t offset
    const int st4 = (tid & 1) * 4;      // st half

    // issue ALL target loads up front; latency hides under staging+barrier
    float4v tgv[2][3];
#pragma unroll
    for (int rr = 0; rr < 2; ++rr) {
        int t = t0 + rr * 128 + tl;
#pragma unroll
        for (int c = 0; c < 3; ++c) {
            size_t obase = (((size_t)bt * 3 + c) * LO + t) * 8 + st4;
            tgv[rr][c] = *(const float4v*)(targets + obase);
        }
    }

    // stage 24 rows x 132 floats (i0-1 .. i0+130), batched 4 deep
    const bool interior = (i0 >= 1) && (i0 + 130 <= L - 1);
    if (interior) {
        for (int base = tid; base < 24 * 33; base += 1024) {
            float4v vv[4]; int ro[4], qd[4]; bool val[4];
#pragma unroll
            for (int u = 0; u < 4; ++u) {
                int idx = base + u * 256;
                val[u] = idx < 24 * 33;
                int id2 = val[u] ? idx : 0;
                int row = id2 / 33;
                int q = id2 - row * 33;
                int c = row >> 3, s = row & 7;
                const float* src = h4 + ((size_t)(bt * 8 + s) * 3 + c) * L;
                vv[u] = ((const f4u*)(src + (i0 - 1 + 4 * q)))->v;
                ro[u] = row; qd[u] = q;
            }
#pragma unroll
            for (int u = 0; u < 4; ++u)
                if (val[u]) *(float4v*)(sh + ro[u] * 132 + 4 * qd[u]) = vv[u];
        }
    } else {
        for (int idx = tid; idx < 24 * 33; idx += 256) {
            int row = idx / 33;
            int q = idx - row * 33;
            int c = row >> 3, s = row & 7;
            const float* src = h4 + ((size_t)(bt * 8 + s) * 3 + c) * L;
            int bi0 = i0 - 1 + 4 * q;
            float4v v;
#pragma unroll
            for (int k = 0; k < 4; ++k) {
                int bi = bi0 + k;
                bi = bi < 0 ? 0 : (bi > L - 1 ? L - 1 : bi);
                v[k] = src[bi];
            }
            *(float4v*)(sh + row * 132 + 4 * q) = v;
        }
    }
    if (tid < 8) snz[tid] = 0;
    __syncthreads();

    float lsum = 0.f;
    int nzm = 0;
#pragma unroll
    for (int rr = 0; rr < 2; ++rr) {
        int t = t0 + rr * 128 + tl;
        int li = (t >> 1) - i0 + 1;
        float o[3][4];
#pragma unroll
        for (int c = 0; c < 3; ++c)
#pragma unroll
            for (int s = 0; s < 4; ++s) {
                const float* row = sh + ((c << 3) + st4 + s) * 132;
                float v;
                if (t & 1) v = 0.75f * row[li] + 0.25f * row[li + 1];
                else       v = 0.25f * row[li - 1] + 0.75f * row[li];
                o[c][s] = v;
            }
#pragma unroll
        for (int c = 0; c < 3; ++c) {
            size_t obase = (((size_t)bt * 3 + c) * LO + t) * 8 + st4;
            float4v ov = { o[c][0], o[c][1], o[c][2], o[c][3] };
            *(float4v*)(out + obase) = ov;
        }
#pragma unroll
        for (int s = 0; s < 4; ++s) {
            float a0 = o[0][s], a1 = o[1][s], a2 = o[2][s];
            float mx = fmaxf(a0, fmaxf(a1, a2));
            float e0 = __expf(a0 - mx), e1 = __expf(a1 - mx), e2 = __expf(a2 - mx);
            float lse = mx + __logf(e0 + e1 + e2);
            float g0 = tgv[rr][0][s], g1 = tgv[rr][1][s], g2 = tgv[rr][2][s];
            lsum += g0 * (lse - a0) + g1 * (lse - a1) + g2 * (lse - a2);
            if ((g0 != 0.f) | (g1 != 0.f) | (g2 != 0.f)) nzm |= 1 << s;
        }
    }
    if (nzm) {
#pragma unroll
        for (int s = 0; s < 4; ++s) if (nzm & (1 << s)) snz[st4 + s] = 1;
    }

#pragma unroll
    for (int off = 32; off > 0; off >>= 1) lsum += __shfl_down(lsum, off, 64);
    if ((tid & 63) == 0) swv[tid >> 6] = lsum;
    __syncthreads();
    if (tid == 0) atomicAdd(loss_sum, swv[0] + swv[1] + swv[2] + swv[3]);
    if (tid < 8 && snz[tid]) atomicOr(&flags[bt * 8 + tid], 1);
}

__global__ __launch_bounds__(256) void finalize_ker(
    const int* __restrict__ flags, const float* __restrict__ loss_sum,
    float* __restrict__ out_loss)
{
    __shared__ int s[256];
    s[threadIdx.x] = flags[threadIdx.x] ? 1 : 0;
    __syncthreads();
    for (int off = 128; off > 0; off >>= 1) {
        if (threadIdx.x < off) s[threadIdx.x] += s[threadIdx.x + off];
        __syncthreads();
    }
    if (threadIdx.x == 0) out_loss[0] = loss_sum[0] / ((float)s[0] * 32768.0f);
}

extern "C" void kernel_launch(void* const* d_in, const int* in_sizes, int n_in,
                              void* d_out, int out_size, void* d_ws, size_t ws_size,
                              hipStream_t stream)
{
    const float* x  = (const float*)d_in[0];
    const float* tg = (const float*)d_in[1];
    const float* w0 = (const float*)d_in[2];
    const float* g0 = (const float*)d_in[3];
    const float* b0 = (const float*)d_in[4];
    const float* m0 = (const float*)d_in[5];
    const float* v0 = (const float*)d_in[6];
    const float* w1 = (const float*)d_in[7];
    const float* g1 = (const float*)d_in[8];
    const float* b1 = (const float*)d_in[9];
    const float* m1 = (const float*)d_in[10];
    const float* v1 = (const float*)d_in[11];
    const float* w2 = (const float*)d_in[12];
    const float* g2 = (const float*)d_in[13];
    const float* b2 = (const float*)d_in[14];
    const float* m2 = (const float*)d_in[15];
    const float* v2 = (const float*)d_in[16];
    const float* w3 = (const float*)d_in[17];
    const float* g3 = (const float*)d_in[18];
    const float* b3 = (const float*)d_in[19];
    const float* m3 = (const float*)d_in[20];
    const float* v3 = (const float*)d_in[21];
    const float* w_out = (const float*)d_in[22];
    const float* b_out = (const float*)d_in[23];
    float* outp = (float*)d_out;

    char* ws = (char*)d_ws;
    int* flags = (int*)ws;                           // [0,1024)
    float* loss_sum = (float*)(ws + 1024);
    short* wb0 = (short*)(ws + 4096);                // 64 x 640  = 81920 B
    short* wb1 = (short*)(ws + 86016);               // 32 x 320  = 20480 B
    short* wb2 = (short*)(ws + 106496);              // 16 x 160  =  5120 B
    short* wb3 = (short*)(ws + 111616);              // 16 x 96   =  3072 B
    short* wb4 = (short*)(ws + 114688);              // 16 x 64   =  2048 B
    const size_t BUF_OFF = 131072;
    const size_t BUFN = (size_t)16777216;            // floats per ping-pong buffer
    float* bufA = (float*)(ws + BUF_OFF);
    float* bufB = (ws_size >= BUF_OFF + 2 * BUFN * 4)
                      ? (bufA + BUFN)
                      : (float*)d_out;               // d_out as scratch fallback

    hipMemsetAsync(d_ws, 0, 4096, stream);

    wprep_all_ker<<<220, 256, 0, stream>>>(w0, w1, w2, w3, w_out,
                                           wb0, wb1, wb2, wb3, wb4);

    // h0 (256,64,1024)  fp32[c][t]->bf16[t][c], T=128, WT=2/WCO=2, 36KB LDS
    conv_ker<128, 64, 1, 1024, 128, 2, 2, true, 0, 0>
        <<<dim3(256, 8), 256, 0, stream>>>(x, wb0, g0, b0, m0, v0, bufA);
    // h1 (256,32,2048)  T=256, WT=2/WCO=2, 38KB LDS
    conv_ker<64, 32, 2, 2048, 256, 2, 2, true, 1, 0>
        <<<dim3(256, 8), 256, 0, stream>>>(bufA, wb1, g1, b1, m1, v1, bufB);
    // h2 (256,16,4096)  T=512, WT=4/WCO=1, 42KB LDS, full A-preload
    conv_ker<32, 16, 4, 4096, 512, 4, 1, true, 1, 0>
        <<<dim3(256, 8), 256, 0, stream>>>(bufB, wb2, g2, b2, m2, v2, bufA);
    // h3 (256,8,8192)   T=512, WT=4/WCO=1, 26KB LDS, full A-preload
    conv_ker<16, 8, 8, 8192, 512, 4, 1, true, 1, 0>
        <<<dim3(256, 16), 256, 0, stream>>>(bufA, wb3, g3, b3, m3, v3, bufB);
    // h4 (256,3,16384)  T=512, WT=4/WCO=1, 28KB LDS, full A-preload
    conv_ker<8, 3, 16, 16384, 512, 4, 1, false, 1, 1>
        <<<dim3(256, 32), 256, 0, stream>>>(bufB, wb4, b_out, b_out, b_out, b_out, bufA);
    // out + loss
    up_loss_ker<<<dim3(32, 128), 256, 0, stream>>>(bufA, tg, outp, loss_sum, flags);
    finalize_ker<<<1, 256, 0, stream>>>(flags, loss_sum, outp + (size_t)(out_size - 1));
}